// Round 2
// baseline (176.225 us; speedup 1.0000x reference)
//
#include <hip/hip_runtime.h>

#define BATCH 256
#define TT 256
#define DD 384
#define HH 64
#define SCALE 0.125f
#define SHIFT 14.0f

typedef __attribute__((ext_vector_type(8))) short short8;
typedef __attribute__((ext_vector_type(4))) float floatx4;

#define KS_STRIDE 72    // Ks [256][72] bf16: 144B rows
#define QS_STRIDE 72    // Qs [256][72] bf16
#define VT_STRIDE 264   // Vt [64][264] bf16
#define PS_STRIDE 40    // per-wave P scratch [16][40]
#define WELEMS (3 * DD * HH)   // 73,728 bf16 = 147,456 B packed W

__device__ __forceinline__ unsigned short f2bf(float f) {
    unsigned int u = __float_as_uint(f);
    u += 0x7fffu + ((u >> 16) & 1u);
    return (unsigned short)(u >> 16);
}
__device__ __forceinline__ float bf2f(unsigned short u) {
    return __uint_as_float(((unsigned int)u) << 16);
}

// 8 fp32 -> bf16 A-fragment (a[j] = f[j])
__device__ __forceinline__ short8 cvt8(float4 f0, float4 f1) {
    short8 a;
    a[0] = (short)f2bf(f0.x); a[1] = (short)f2bf(f0.y);
    a[2] = (short)f2bf(f0.z); a[3] = (short)f2bf(f0.w);
    a[4] = (short)f2bf(f1.x); a[5] = (short)f2bf(f1.y);
    a[6] = (short)f2bf(f1.z); a[7] = (short)f2bf(f1.w);
    return a;
}

// One block per batch. 512 thr = 8 waves. LDS 147,456 B -> 1 block/CU.
// W is packed fragment-major bf16 into LDS by the block itself (no pack
// kernel, no workspace): U.w[((ch*3+mat)*4+nt)*512 + lane*8 + j] holds
// W_mat[d = 32ch + 8*(lane>>4) + j][h = 16nt + (lane&15)], so a wave's
// B-fragment load is one conflict-free contiguous ds_read_b128.
__global__ __launch_bounds__(512, 2)
void fused_kernel(const float* __restrict__ x,
                  const float* __restrict__ wq,
                  const float* __restrict__ wk,
                  const float* __restrict__ wv,
                  float* __restrict__ out) {
    // Phase 1 uses U.w (full packed W, 147,456 B).
    // Phase 2 buffers alias it (117,760 B) -- first written AFTER the post-loop barrier.
    __shared__ __align__(16) union LdsU {
        unsigned short w[WELEMS];                      // 147,456 B (phase 1)
        struct {
            unsigned short ks[TT * KS_STRIDE];         // 36,864 B
            unsigned short vt[HH * VT_STRIDE];         // 33,792 B
            unsigned short q[TT * QS_STRIDE];          // 36,864 B
            unsigned short p[8][16 * PS_STRIDE];       // 10,240 B
        } s;
    } U;

    const int b = blockIdx.x;
    const int tid = threadIdx.x;
    const int wave = tid >> 6;
    const int lane = tid & 63;
    const int quad = lane >> 4;
    const int l16 = lane & 15;

    const float* xb = x + (size_t)b * TT * DD;

    // Per-lane x source rows for the MFMA A-fragment: lane(l16,quad) supplies
    // x[32*wave + l16][32*ch + 8*quad + j], j=0..7. Across a wave the 4 quads
    // tile a contiguous 128B slice of each of 16 rows.
    const float* xr0 = xb + (size_t)(32 * wave + l16) * DD + 8 * quad;
    const float* xr1 = xr0 + (size_t)16 * DD;

    // ---------------- Phase 1: Q,K,V = x_b @ {Wq,Wk,Wv} ----------------
    floatx4 cq[2][4] = {};
    floatx4 ck[2][4] = {};
    floatx4 cv[2][4] = {};

    float4 xfA[4], xfB[4];

    // Issue chunk-0/1 x loads FIRST so the HBM stream starts immediately and
    // flies under the W packing below (2-chunk-deep register pipeline).
    xfA[0] = *(const float4*)(xr0);
    xfA[1] = *(const float4*)(xr0 + 4);
    xfA[2] = *(const float4*)(xr1);
    xfA[3] = *(const float4*)(xr1 + 4);
    xfB[0] = *(const float4*)(xr0 + 32);
    xfB[1] = *(const float4*)(xr0 + 36);
    xfB[2] = *(const float4*)(xr1 + 32);
    xfB[3] = *(const float4*)(xr1 + 36);

    // In-block W pack: 9216 granules of 8 bf16; thread t fills granules
    // t, t+512, ... (18 each). Source reads are L3-resident fp32 (294 KB
    // shared by all 256 blocks); one ds_write_b128 per granule.
    for (int g = 0; g < 18; ++g) {
        int gidx = g * 512 + tid;
        int laneg = gidx & 63;
        int nt = (gidx >> 6) & 3;
        int rem = gidx >> 8;               // ch*3 + mat, 0..35
        int mat = rem % 3;
        int ch = rem / 3;
        int l16g = laneg & 15, qg = laneg >> 4;
        const float* w = (mat == 0) ? wq : (mat == 1) ? wk : wv;
        const float* src = w + (size_t)(32 * ch + 8 * qg) * HH + 16 * nt + l16g;
        short8 pk;
        #pragma unroll
        for (int j = 0; j < 8; ++j)
            pk[j] = (short)f2bf(src[(size_t)j * HH]);
        *(short8*)(U.w + (size_t)gidx * 8) = pk;
    }

    __syncthreads();   // W packed (lgkm drained); x ch0/1 frags in flight/landed

    // Chunk body: consume BUF (ch), then reload BUF with ch+2 (2-deep pipe),
    // read 12 W B-fragments from LDS, 24 MFMAs. No barriers inside the loop.
    #define GEMM_BODY(BUF, CH)                                                     \
        {                                                                          \
            short8 a0 = cvt8(BUF[0], BUF[1]);                                      \
            short8 a1 = cvt8(BUF[2], BUF[3]);                                      \
            if ((CH) + 2 < 12) {                                                   \
                const float* p0_ = xr0 + ((CH) + 2) * 32;                          \
                const float* p1_ = xr1 + ((CH) + 2) * 32;                          \
                BUF[0] = *(const float4*)(p0_);                                    \
                BUF[1] = *(const float4*)(p0_ + 4);                                \
                BUF[2] = *(const float4*)(p1_);                                    \
                BUF[3] = *(const float4*)(p1_ + 4);                                \
            }                                                                      \
            short8 wf_[12];                                                        \
            _Pragma("unroll")                                                      \
            for (int i = 0; i < 12; ++i)                                           \
                wf_[i] = *(const short8*)(U.w + (size_t)((CH) * 12 + i) * 512 + lane * 8); \
            _Pragma("unroll")                                                      \
            for (int nt = 0; nt < 4; ++nt) {                                       \
                cq[0][nt] = __builtin_amdgcn_mfma_f32_16x16x32_bf16(a0, wf_[nt], cq[0][nt], 0, 0, 0);      \
                cq[1][nt] = __builtin_amdgcn_mfma_f32_16x16x32_bf16(a1, wf_[nt], cq[1][nt], 0, 0, 0);      \
                ck[0][nt] = __builtin_amdgcn_mfma_f32_16x16x32_bf16(a0, wf_[4 + nt], ck[0][nt], 0, 0, 0);  \
                ck[1][nt] = __builtin_amdgcn_mfma_f32_16x16x32_bf16(a1, wf_[4 + nt], ck[1][nt], 0, 0, 0);  \
                cv[0][nt] = __builtin_amdgcn_mfma_f32_16x16x32_bf16(a0, wf_[8 + nt], cv[0][nt], 0, 0, 0);  \
                cv[1][nt] = __builtin_amdgcn_mfma_f32_16x16x32_bf16(a1, wf_[8 + nt], cv[1][nt], 0, 0, 0);  \
            }                                                                      \
        }

    #pragma unroll 1
    for (int t = 0; t < 6; ++t) {
        GEMM_BODY(xfA, 2 * t);
        GEMM_BODY(xfB, 2 * t + 1);
    }
    #undef GEMM_BODY

    __syncthreads();   // all W-fragment reads done before overlaying with Ks/Vt/Q

    // C layout: row = 4*quad + r, col = 16*nt + l16
    #pragma unroll
    for (int mi = 0; mi < 2; ++mi)
      #pragma unroll
      for (int nt = 0; nt < 4; ++nt)
        #pragma unroll
        for (int r = 0; r < 4; ++r) {
            int row = 32 * wave + 16 * mi + 4 * quad + r;
            int col = 16 * nt + l16;
            U.s.q[row * QS_STRIDE + col] = f2bf(cq[mi][nt][r]);
            U.s.ks[row * KS_STRIDE + col] = f2bf(ck[mi][nt][r]);
            U.s.vt[col * VT_STRIDE + row] = f2bf(cv[mi][nt][r]);
        }

    __syncthreads();

    // ---------------- Phase 2: causal attention, fixed-shift softmax ----------------
    // wave handles row-groups g = wave and g = 15-wave: 9 key-chunks total (balanced).
    floatx4 o[2][4] = {};
    float l_run[2][4] = {{0.f, 0.f, 0.f, 0.f}, {0.f, 0.f, 0.f, 0.f}};
    unsigned short* psw = U.s.p[wave];

    #pragma unroll
    for (int gi = 0; gi < 2; ++gi) {
        int g = gi ? (15 - wave) : wave;
        int gr0 = 16 * g;
        short8 aq0 = *(const short8*)(U.s.q + (size_t)(gr0 + l16) * QS_STRIDE + quad * 8);
        short8 aq1 = *(const short8*)(U.s.q + (size_t)(gr0 + l16) * QS_STRIDE + 32 + quad * 8);
        int clast = g >> 1;
        for (int c = 0; c <= clast; ++c) {
            floatx4 s[2] = {};
            #pragma unroll
            for (int ni = 0; ni < 2; ++ni) {
                const unsigned short* kbase =
                    U.s.ks + (size_t)(32 * c + 16 * ni + l16) * KS_STRIDE + quad * 8;
                s[ni] = __builtin_amdgcn_mfma_f32_16x16x32_bf16(aq0, *(const short8*)(kbase), s[ni], 0, 0, 0);
                s[ni] = __builtin_amdgcn_mfma_f32_16x16x32_bf16(aq1, *(const short8*)(kbase + 32), s[ni], 0, 0, 0);
            }
            bool partial = (c == clast);
            #pragma unroll
            for (int r = 0; r < 4; ++r) {
                int row = gr0 + 4 * quad + r;
                float p0 = __expf(s[0][r] * SCALE - SHIFT);
                float p1 = __expf(s[1][r] * SCALE - SHIFT);
                if (partial) {
                    if (32 * c + l16 > row) p0 = 0.f;
                    if (32 * c + 16 + l16 > row) p1 = 0.f;
                }
                unsigned short b0 = f2bf(p0), b1 = f2bf(p1);
                l_run[gi][r] += bf2f(b0) + bf2f(b1);   // consistent with bf16 P fed to PV
                psw[(4 * quad + r) * PS_STRIDE + l16] = b0;
                psw[(4 * quad + r) * PS_STRIDE + 16 + l16] = b1;
            }
            short8 ap = *(const short8*)(psw + l16 * PS_STRIDE + quad * 8);
            #pragma unroll
            for (int nt = 0; nt < 4; ++nt) {
                short8 bv = *(const short8*)(U.s.vt + (size_t)(16 * nt + l16) * VT_STRIDE + 32 * c + quad * 8);
                o[gi][nt] = __builtin_amdgcn_mfma_f32_16x16x32_bf16(ap, bv, o[gi][nt], 0, 0, 0);
            }
        }
    }

    // ---------------- Epilogue: one l-reduction + one reciprocal per row ----------------
    float* outb = out + (size_t)b * TT * HH;
    #pragma unroll
    for (int gi = 0; gi < 2; ++gi) {
        int g = gi ? (15 - wave) : wave;
        float linv[4];
        #pragma unroll
        for (int r = 0; r < 4; ++r) {
            float l = l_run[gi][r];
            l += __shfl_xor(l, 1);
            l += __shfl_xor(l, 2);
            l += __shfl_xor(l, 4);
            l += __shfl_xor(l, 8);
            linv[r] = 1.0f / l;
        }
        #pragma unroll
        for (int nt = 0; nt < 4; ++nt)
          #pragma unroll
          for (int r = 0; r < 4; ++r) {
            int row = 16 * g + 4 * quad + r;
            outb[(size_t)row * HH + 16 * nt + l16] = o[gi][nt][r] * linv[r];
          }
    }
}

extern "C" void kernel_launch(void* const* d_in, const int* in_sizes, int n_in,
                              void* d_out, int out_size, void* d_ws, size_t ws_size,
                              hipStream_t stream) {
    const float* x  = (const float*)d_in[0];
    const float* wq = (const float*)d_in[1];
    const float* wk = (const float*)d_in[2];
    const float* wv = (const float*)d_in[3];
    float* o = (float*)d_out;
    (void)d_ws; (void)ws_size;

    fused_kernel<<<BATCH, 512, 0, stream>>>(x, wq, wk, wv, o);
}